// Round 8
// baseline (101.270 us; speedup 1.0000x reference)
//
#include <hip/hip_runtime.h>
#include <hip/hip_cooperative_groups.h>
#include <math.h>

namespace cg = cooperative_groups;

#define NB 16
#define NA 19200
#define NT 50
#define NC 80
#define LAMBDA_COORD 5.0f
#define F_EPS 1e-6f

#define GRID 256
#define THREADS 1024
#define GSTRIDE (GRID * THREADS)      // 262144
#define WAVES (THREADS / 64)          // 16

// ws layout: [0..1024) float part[256]; [1024..4224) int best_idx[800]

__device__ __forceinline__ float bce0(float x) {          // bce_logits(x, 0)
    return fmaxf(x, 0.0f) + log1pf(expf(-fabsf(x)));
}

__global__ __launch_bounds__(1024) void yolo_all_kernel(
        const float* __restrict__ pb,
        const float* __restrict__ pc,
        const float* __restrict__ pcls,
        const float* __restrict__ tb,
        const int* __restrict__ tl,
        int* __restrict__ best_idx,
        float* __restrict__ part,
        float* __restrict__ out) {
    const float W_OBJ = 1.0f / (float)(NB * NA);
    const float W_BOX = LAMBDA_COORD / (float)(NB * NT);
    const float W_CLS = 1.0f / (float)(NB * NT * NC);

    cg::grid_group grid = cg::this_grid();
    const int tid = threadIdx.x;
    const int blk = blockIdx.x;
    const int wave = tid >> 6;
    const int lane = tid & 63;

    const float4* pb4 = (const float4*)pb;
    const float4* tb4 = (const float4*)tb;

    __shared__ float swv[WAVES][4];
    __shared__ int   swi[WAVES][4];
    __shared__ float swred[WAVES];

    // ================= Phase 1: argmax (16 blocks per image) =================
    {
        const int b   = blk >> 4;
        const int sub = blk & 15;
        const int t0  = sub * 3 + (sub < 2 ? sub : 2);   // subs 0,1 -> 4 targets; rest 3
        const int ntg = 3 + (sub < 2 ? 1 : 0);

        float4 t4[4]; float ta[4];
        #pragma unroll
        for (int i = 0; i < 4; ++i) {
            int tt = t0 + (i < ntg ? i : ntg - 1);       // pad with last real target
            t4[i] = tb4[b * NT + tt];
            ta[i] = (t4[i].z - t4[i].x) * (t4[i].w - t4[i].y);
        }

        float best[4]; int bidx[4];
        #pragma unroll
        for (int i = 0; i < 4; ++i) { best[i] = -1.0f; bidx[i] = NA; }

        for (int a = tid; a < NA; a += THREADS) {        // ascending -> first-idx ties kept
            float4 p = pb4[(size_t)b * NA + a];
            float area1 = (p.z - p.x) * (p.w - p.y);
            #pragma unroll
            for (int i = 0; i < 4; ++i) {
                float ix1 = fmaxf(p.x, t4[i].x), iy1 = fmaxf(p.y, t4[i].y);
                float ix2 = fminf(p.z, t4[i].z), iy2 = fminf(p.w, t4[i].w);
                float inter = fmaxf(ix2 - ix1, 0.0f) * fmaxf(iy2 - iy1, 0.0f);
                float iou = inter / (area1 + ta[i] - inter + F_EPS);
                if (iou > best[i]) { best[i] = iou; bidx[i] = a; }
            }
        }

        #pragma unroll
        for (int i = 0; i < 4; ++i) {
            float v = best[i];
            int   ix = bidx[i];
            #pragma unroll
            for (int m = 1; m < 64; m <<= 1) {
                float ov = __shfl_xor(v, m);
                int   oi = __shfl_xor(ix, m);
                if (ov > v || (ov == v && oi < ix)) { v = ov; ix = oi; }
            }
            if (lane == 0) { swv[wave][i] = v; swi[wave][i] = ix; }
        }
        __syncthreads();

        if (tid < ntg) {
            float v = swv[0][tid];
            int   ix = swi[0][tid];
            #pragma unroll
            for (int w = 1; w < WAVES; ++w) {
                float ov = swv[w][tid];
                int   oi = swi[w][tid];
                if (ov > v || (ov == v && oi < ix)) { v = ov; ix = oi; }
            }
            best_idx[b * NT + t0 + tid] = ix;
            __threadfence();                             // device-scope visibility
        }
    }

    grid.sync();

    // ================= Phase 2: all loss terms, weighted per-thread acc =================
    const int gtid = blk * THREADS + tid;
    float s = 0.0f;

    // ---- objectness bulk: sum bce(x, 0) over ALL anchors (no mask needed) ----
    for (int i = gtid; i < NB * NA; i += GSTRIDE)
        s += W_OBJ * bce0(pc[i]);

    // ---- class BCE over (b,t,c): bce(x,z) = bce0(x) - x*z ----
    if (gtid < NB * NT * NC) {
        const int bt = gtid / NC;
        const int c  = gtid - bt * NC;
        const int b  = bt / NT;
        float x = pcls[((size_t)b * NA + best_idx[bt]) * NC + c];
        s += W_CLS * (bce0(x) - (tl[bt] == c ? x : 0.0f));
    }

    // ---- CIoU + objectness correction over (b,t) ----
    if (gtid < NB * NT) {
        const int bt = gtid;
        const int b  = bt / NT;
        const int t  = bt - b * NT;
        const int bi = best_idx[bt];

        // obj correction: bce(x,1) - bce(x,0) = -x, once per UNIQUE best anchor
        bool dup = false;
        for (int tp = 0; tp < t; ++tp)
            if (best_idx[b * NT + tp] == bi) dup = true;
        if (!dup) s -= W_OBJ * pc[(size_t)b * NA + bi];

        const float* p  = pb + ((size_t)b * NA + bi) * 4;
        const float* tg = tb + (size_t)bt * 4;
        float b1x1 = p[0],  b1y1 = p[1],  b1x2 = p[2],  b1y2 = p[3];
        float b2x1 = tg[0], b2y1 = tg[1], b2x2 = tg[2], b2y2 = tg[3];

        float area1 = (b1x2 - b1x1) * (b1y2 - b1y1);
        float area2 = (b2x2 - b2x1) * (b2y2 - b2y1);
        float iw = fmaxf(fminf(b1x2, b2x2) - fmaxf(b1x1, b2x1), 0.0f);
        float ih = fmaxf(fminf(b1y2, b2y2) - fmaxf(b1y1, b2y1), 0.0f);
        float inter = iw * ih;
        float iou = inter / (area1 + area2 - inter + F_EPS);

        float cdx = fmaxf(b1x2, b2x2) - fminf(b1x1, b2x1);
        float cdy = fmaxf(b1y2, b2y2) - fminf(b1y1, b2y1);
        float c_diag = cdx * cdx + cdy * cdy;

        float cx = (b1x1 + b1x2 - b2x1 - b2x2) * 0.5f;
        float cy = (b1y1 + b1y2 - b2y1 - b2y2) * 0.5f;
        float center_dist = cx * cx + cy * cy;

        float w1 = b1x2 - b1x1, h1 = b1y2 - b1y1;
        float w2 = b2x2 - b2x1, h2 = b2y2 - b2y1;
        float dat = atanf(w2 / h2) - atanf(w1 / h1);
        float vv = (float)(4.0 / (M_PI * M_PI)) * dat * dat;
        float alpha = vv / (1.0f - iou + vv + F_EPS);
        float ciou = iou - center_dist / c_diag - alpha * vv;
        s += W_BOX * (1.0f - ciou);
    }

    // ---- block reduce: wave shfl + cross-wave LDS ----
    #pragma unroll
    for (int m = 32; m > 0; m >>= 1) s += __shfl_down(s, m);
    if (lane == 0) swred[wave] = s;
    __syncthreads();
    if (tid < WAVES) {
        float v = swred[tid];
        #pragma unroll
        for (int m = 8; m > 0; m >>= 1) v += __shfl_down(v, m);
        if (tid == 0) part[blk] = v;
    }

    grid.sync();

    // ---- block 0 sums the 256 partials ----
    if (blk == 0) {
        float v = (tid < GRID) ? part[tid] : 0.0f;
        #pragma unroll
        for (int m = 32; m > 0; m >>= 1) v += __shfl_down(v, m);
        if (lane == 0) swred[wave] = v;
        __syncthreads();
        if (tid == 0) {
            float r = 0.0f;
            #pragma unroll
            for (int w = 0; w < WAVES; ++w) r += swred[w];
            out[0] = r;
        }
    }
}

extern "C" void kernel_launch(void* const* d_in, const int* in_sizes, int n_in,
                              void* d_out, int out_size, void* d_ws, size_t ws_size,
                              hipStream_t stream) {
    const float* pb   = (const float*)d_in[0];   // (B,A,4)
    const float* pc   = (const float*)d_in[1];   // (B,A,1)
    const float* pcls = (const float*)d_in[2];   // (B,A,C)
    const float* tb   = (const float*)d_in[3];   // (B,T,4)
    const int*   tl   = (const int*)d_in[4];     // (B,T)

    char* ws = (char*)d_ws;
    float* part     = (float*)ws;                // 256 floats
    int*   best_idx = (int*)(ws + 1024);         // 800 ints
    float* outp     = (float*)d_out;

    void* args[] = { (void*)&pb, (void*)&pc, (void*)&pcls, (void*)&tb, (void*)&tl,
                     (void*)&best_idx, (void*)&part, (void*)&outp };
    hipLaunchCooperativeKernel((void*)yolo_all_kernel, dim3(GRID), dim3(THREADS),
                               args, 0, stream);
}

// Round 9
// 59.815 us; speedup vs baseline: 1.6930x; 1.6930x over previous
//
#include <hip/hip_runtime.h>
#include <math.h>

#define NB 16
#define NA 19200
#define NT 50
#define NC 80
#define LAMBDA_COORD 5.0f
#define F_EPS 1e-6f

// D1: block = (image, anchor-chunk). Each anchor read ONCE from global.
#define NCH 16                 // anchor chunks per image
#define CH_A (NA / NCH)        // 1200 anchors per chunk
#define D1_THREADS 512
#define D1_BLOCKS (NB * NCH)   // 256 = one per CU
#define D1_WAVES (D1_THREADS / 64)
#define TG 10                  // targets per register pass
#define NPASS (NT / TG)        // 5

// D2: one block per image.
#define D2_THREADS 1024
#define D2_WAVES (D2_THREADS / 64)

#define W_OBJ (1.0f / (float)(NB * NA))
#define W_BOX (LAMBDA_COORD / (float)(NB * NT))
#define W_CLS (1.0f / (float)(NB * NT * NC))

// ws layout:
// [0     .. 1024)   float part_obj[256]
// [1024  .. 52224)  float val_part[NB*NT*NCH]  (12800)
// [52224 .. 103424) int   idx_part[NB*NT*NCH]

__device__ __forceinline__ float bce0(float x) {   // bce_logits(x, 0)
    return fmaxf(x, 0.0f) + log1pf(expf(-fabsf(x)));
}

// ------------------- D1: chunked argmax + bulk objectness -------------------
__global__ __launch_bounds__(512) void d1_kernel(
        const float4* __restrict__ pb4,
        const float4* __restrict__ tb4,
        const float4* __restrict__ pc4,
        float* __restrict__ val_part,
        int* __restrict__ idx_part,
        float* __restrict__ part_obj,
        float* __restrict__ out) {
    const int blk = blockIdx.x;
    const int b   = blk >> 4;          // image
    const int ch  = blk & (NCH - 1);   // anchor chunk
    const int tid = threadIdx.x;
    const int wave = tid >> 6;
    const int lane = tid & 63;

    if (blk == 0 && tid == 0) out[0] = 0.0f;   // D2 adds after stream-order boundary

    __shared__ float4 sanc[CH_A];              // 19.2 KB anchor stage
    __shared__ float4 stb[NT];
    __shared__ float  sarea[NT];
    __shared__ float  swv[D1_WAVES][TG];
    __shared__ int    swi[D1_WAVES][TG];
    __shared__ float  sobj[D1_WAVES];

    for (int i = tid; i < CH_A; i += D1_THREADS)
        sanc[i] = pb4[(size_t)b * NA + ch * CH_A + i];
    if (tid < NT) {
        float4 t4 = tb4[b * NT + tid];
        stb[tid] = t4;
        sarea[tid] = (t4.z - t4.x) * (t4.w - t4.y);
    }
    __syncthreads();

    for (int p = 0; p < NPASS; ++p) {
        // targets of this pass in registers
        float4 t4[TG]; float ta[TG];
        #pragma unroll
        for (int g = 0; g < TG; ++g) {
            t4[g] = stb[p * TG + g];
            ta[g] = sarea[p * TG + g];
        }

        float best[TG]; int bidx[TG];
        #pragma unroll
        for (int g = 0; g < TG; ++g) { best[g] = -1.0f; bidx[g] = NA; }

        for (int al = tid; al < CH_A; al += D1_THREADS) {   // ascending -> first-idx ties
            float4 pq = sanc[al];
            float area1 = (pq.z - pq.x) * (pq.w - pq.y);
            const int gidx = ch * CH_A + al;
            #pragma unroll
            for (int g = 0; g < TG; ++g) {
                float ix1 = fmaxf(pq.x, t4[g].x), iy1 = fmaxf(pq.y, t4[g].y);
                float ix2 = fminf(pq.z, t4[g].z), iy2 = fminf(pq.w, t4[g].w);
                float inter = fmaxf(ix2 - ix1, 0.0f) * fmaxf(iy2 - iy1, 0.0f);
                float iou = inter / (area1 + ta[g] - inter + F_EPS);
                if (iou > best[g]) { best[g] = iou; bidx[g] = gidx; }
            }
        }

        // wave butterfly (max val, tie -> min idx)
        #pragma unroll
        for (int g = 0; g < TG; ++g) {
            float v = best[g];
            int   ix = bidx[g];
            #pragma unroll
            for (int m = 1; m < 64; m <<= 1) {
                float ov = __shfl_xor(v, m);
                int   oi = __shfl_xor(ix, m);
                if (ov > v || (ov == v && oi < ix)) { v = ov; ix = oi; }
            }
            if (lane == 0) { swv[wave][g] = v; swi[wave][g] = ix; }
        }
        __syncthreads();

        if (tid < TG) {
            float v = swv[0][tid];
            int   ix = swi[0][tid];
            #pragma unroll
            for (int w = 1; w < D1_WAVES; ++w) {
                float ov = swv[w][tid];
                int   oi = swi[w][tid];
                if (ov > v || (ov == v && oi < ix)) { v = ov; ix = oi; }
            }
            const int t = p * TG + tid;
            val_part[((size_t)b * NT + t) * NCH + ch] = v;
            idx_part[((size_t)b * NT + t) * NCH + ch] = ix;
        }
        __syncthreads();   // swv/swi reused next pass
    }

    // ---- bulk objectness: sum bce0 over this block's 300 float4s of pc ----
    float s = 0.0f;
    if (tid < 300) {
        float4 v4 = pc4[blk * 300 + tid];   // 256*300*4 = 307200 exactly
        s = bce0(v4.x) + bce0(v4.y) + bce0(v4.z) + bce0(v4.w);
    }
    #pragma unroll
    for (int m = 32; m > 0; m >>= 1) s += __shfl_down(s, m);
    if (lane == 0) sobj[wave] = s;
    __syncthreads();
    if (tid == 0) {
        float r = 0.0f;
        #pragma unroll
        for (int w = 0; w < D1_WAVES; ++w) r += sobj[w];
        part_obj[blk] = r * W_OBJ;
    }
}

// ------------- D2: per-image merge + cls BCE + CIoU + obj correction -------------
__global__ __launch_bounds__(1024) void d2_kernel(
        const float* __restrict__ pb,
        const float* __restrict__ pc,
        const float* __restrict__ pcls,
        const float* __restrict__ tb,
        const int* __restrict__ tl,
        const float* __restrict__ val_part,
        const int* __restrict__ idx_part,
        const float* __restrict__ part_obj,
        float* __restrict__ out) {
    const int b   = blockIdx.x;
    const int tid = threadIdx.x;
    const int wave = tid >> 6;
    const int lane = tid & 63;

    __shared__ int   sbi[NT];
    __shared__ int   slab[NT];
    __shared__ float sred[D2_WAVES];

    float s = 0.0f;

    // this block's slice of bulk-obj partials
    if (tid < NCH) s += part_obj[b * NCH + tid];

    // merge the 16 chunk partials per target (ascending chunk -> min global idx on tie)
    if (tid < NT) {
        const size_t base = ((size_t)b * NT + tid) * NCH;
        float v = val_part[base];
        int   ix = idx_part[base];
        for (int c = 1; c < NCH; ++c) {
            float ov = val_part[base + c];
            int   oi = idx_part[base + c];
            if (ov > v || (ov == v && oi < ix)) { v = ov; ix = oi; }
        }
        sbi[tid]  = ix;
        slab[tid] = tl[b * NT + tid];
    }
    __syncthreads();

    if (tid < NT) {
        const int bi = sbi[tid];

        // obj correction: bce(x,1)-bce(x,0) = -x, once per UNIQUE best anchor
        bool dup = false;
        for (int tp = 0; tp < tid; ++tp)
            if (sbi[tp] == bi) dup = true;
        if (!dup) s -= W_OBJ * pc[(size_t)b * NA + bi];

        // CIoU (exact reference formula)
        const float* p  = pb + ((size_t)b * NA + bi) * 4;
        const float* tg = tb + ((size_t)b * NT + tid) * 4;
        float b1x1 = p[0],  b1y1 = p[1],  b1x2 = p[2],  b1y2 = p[3];
        float b2x1 = tg[0], b2y1 = tg[1], b2x2 = tg[2], b2y2 = tg[3];

        float area1 = (b1x2 - b1x1) * (b1y2 - b1y1);
        float area2 = (b2x2 - b2x1) * (b2y2 - b2y1);
        float iw = fmaxf(fminf(b1x2, b2x2) - fmaxf(b1x1, b2x1), 0.0f);
        float ih = fmaxf(fminf(b1y2, b2y2) - fmaxf(b1y1, b2y1), 0.0f);
        float inter = iw * ih;
        float iou = inter / (area1 + area2 - inter + F_EPS);

        float cdx = fmaxf(b1x2, b2x2) - fminf(b1x1, b2x1);
        float cdy = fmaxf(b1y2, b2y2) - fminf(b1y1, b2y1);
        float c_diag = cdx * cdx + cdy * cdy;

        float cx = (b1x1 + b1x2 - b2x1 - b2x2) * 0.5f;
        float cy = (b1y1 + b1y2 - b2y1 - b2y2) * 0.5f;
        float center_dist = cx * cx + cy * cy;

        float w1 = b1x2 - b1x1, h1 = b1y2 - b1y1;
        float w2 = b2x2 - b2x1, h2 = b2y2 - b2y1;
        float dat = atanf(w2 / h2) - atanf(w1 / h1);
        float vv = (float)(4.0 / (M_PI * M_PI)) * dat * dat;
        float alpha = vv / (1.0f - iou + vv + F_EPS);
        float ciou = iou - center_dist / c_diag - alpha * vv;
        s += W_BOX * (1.0f - ciou);
    }

    // class BCE: bce(x,z) = bce0(x) - x*z over NT*NC = 4000 elems
    for (int i = tid; i < NT * NC; i += D2_THREADS) {
        const int t = i / NC;
        const int c = i - t * NC;
        float x = pcls[((size_t)b * NA + sbi[t]) * NC + c];
        s += W_CLS * (bce0(x) - (slab[t] == c ? x : 0.0f));
    }

    // block reduce -> one atomic per block (16 total)
    #pragma unroll
    for (int m = 32; m > 0; m >>= 1) s += __shfl_down(s, m);
    if (lane == 0) sred[wave] = s;
    __syncthreads();
    if (tid == 0) {
        float r = 0.0f;
        #pragma unroll
        for (int w = 0; w < D2_WAVES; ++w) r += sred[w];
        atomicAdd(out, r);
    }
}

extern "C" void kernel_launch(void* const* d_in, const int* in_sizes, int n_in,
                              void* d_out, int out_size, void* d_ws, size_t ws_size,
                              hipStream_t stream) {
    const float* pb   = (const float*)d_in[0];   // (B,A,4)
    const float* pc   = (const float*)d_in[1];   // (B,A,1)
    const float* pcls = (const float*)d_in[2];   // (B,A,C)
    const float* tb   = (const float*)d_in[3];   // (B,T,4)
    const int*   tl   = (const int*)d_in[4];     // (B,T)

    char* ws = (char*)d_ws;
    float* part_obj = (float*)ws;                 // 256 floats
    float* val_part = (float*)(ws + 1024);        // 12800 floats
    int*   idx_part = (int*)(ws + 52224);         // 12800 ints

    d1_kernel<<<D1_BLOCKS, D1_THREADS, 0, stream>>>(
        (const float4*)pb, (const float4*)tb, (const float4*)pc,
        val_part, idx_part, part_obj, (float*)d_out);
    d2_kernel<<<NB, D2_THREADS, 0, stream>>>(
        pb, pc, pcls, tb, tl, val_part, idx_part, part_obj, (float*)d_out);
}

// Round 10
// 41.668 us; speedup vs baseline: 2.4304x; 1.4355x over previous
//
#include <hip/hip_runtime.h>
#include <math.h>

#define NB 16
#define NA 19200
#define NT 50
#define NC 80
#define LAMBDA_COORD 5.0f
#define F_EPS 1e-6f

// Node A: r6-proven argmax structure. block = (image, group of TPG targets).
#define TPG 5
#define NGRP (NT / TPG)          // 10
#define KA_BLOCKS (NB * NGRP)    // 160
#define KA_THREADS 1024
#define KA_WAVES (KA_THREADS / 64)
#define OBJ_F4_PER_BLK (NB * NA / 4 / KA_BLOCKS)   // 480 float4s of pc per block

#define W_OBJ (1.0f / (float)(NB * NA))
#define W_BOX (LAMBDA_COORD / (float)(NB * NT))
#define W_CLS (1.0f / (float)(NB * NT * NC))

// ws layout: [0..1024) float part[160]; [1024..4224) int best_idx[800]

__device__ __forceinline__ float bce0(float x) {   // bce_logits(x, 0)
    return fmaxf(x, 0.0f) + log1pf(expf(-fabsf(x)));
}

// ---- Node A: argmax (r6 body) + per-target CIoU + cls BCE + bulk obj slice ----
__global__ __launch_bounds__(1024) void kA(
        const float* __restrict__ pb,
        const float* __restrict__ pc,
        const float* __restrict__ pcls,
        const float* __restrict__ tb,
        const int* __restrict__ tl,
        int* __restrict__ best_idx,
        float* __restrict__ part) {
    const float4* pb4 = (const float4*)pb;
    const float4* tb4 = (const float4*)tb;
    const float4* pc4 = (const float4*)pc;

    const int b   = blockIdx.x / NGRP;
    const int g   = blockIdx.x % NGRP;
    const int tid = threadIdx.x;
    const int wave = tid >> 6;
    const int lane = tid & 63;

    // ---------- argmax over all anchors for TPG targets (r6-proven) ----------
    float4 t4[TPG];
    float  ta[TPG];
    #pragma unroll
    for (int i = 0; i < TPG; ++i) {
        t4[i] = tb4[b * NT + g * TPG + i];
        ta[i] = (t4[i].z - t4[i].x) * (t4[i].w - t4[i].y);
    }

    float best[TPG];
    int   bidx[TPG];
    #pragma unroll
    for (int i = 0; i < TPG; ++i) { best[i] = -1.0f; bidx[i] = NA; }

    for (int a = tid; a < NA; a += KA_THREADS) {       // ascending -> first-idx ties kept
        float4 p = pb4[(size_t)b * NA + a];
        float area1 = (p.z - p.x) * (p.w - p.y);
        #pragma unroll
        for (int i = 0; i < TPG; ++i) {
            float ix1 = fmaxf(p.x, t4[i].x), iy1 = fmaxf(p.y, t4[i].y);
            float ix2 = fminf(p.z, t4[i].z), iy2 = fminf(p.w, t4[i].w);
            float inter = fmaxf(ix2 - ix1, 0.0f) * fmaxf(iy2 - iy1, 0.0f);
            float iou = inter / (area1 + ta[i] - inter + F_EPS);
            if (iou > best[i]) { best[i] = iou; bidx[i] = a; }
        }
    }

    __shared__ float swv[KA_WAVES][TPG];
    __shared__ int   swi[KA_WAVES][TPG];
    __shared__ int   sbi5[TPG];
    __shared__ float swred[KA_WAVES];

    #pragma unroll
    for (int i = 0; i < TPG; ++i) {
        float v = best[i];
        int   ix = bidx[i];
        #pragma unroll
        for (int m = 1; m < 64; m <<= 1) {
            float ov = __shfl_xor(v, m);
            int   oi = __shfl_xor(ix, m);
            if (ov > v || (ov == v && oi < ix)) { v = ov; ix = oi; }
        }
        if (lane == 0) { swv[wave][i] = v; swi[wave][i] = ix; }
    }
    __syncthreads();

    if (tid < TPG) {
        float v = swv[0][tid];
        int   ix = swi[0][tid];
        #pragma unroll
        for (int w = 1; w < KA_WAVES; ++w) {
            float ov = swv[w][tid];
            int   oi = swi[w][tid];
            if (ov > v || (ov == v && oi < ix)) { v = ov; ix = oi; }
        }
        best_idx[b * NT + g * TPG + tid] = ix;
        sbi5[tid] = ix;
    }
    __syncthreads();

    // ---------- epilogue: weighted per-thread accumulator ----------
    float s = 0.0f;

    // cls BCE for this block's 5 targets: 400 threads, one (t,c) each
    if (tid < TPG * NC) {
        const int t = tid / NC;
        const int c = tid - t * NC;
        float x = pcls[((size_t)b * NA + sbi5[t]) * NC + c];
        int lab = tl[b * NT + g * TPG + t];
        s += W_CLS * (bce0(x) - (lab == c ? x : 0.0f));
    }

    // CIoU for this block's 5 targets (threads 512..516, exact reference formula)
    if (tid >= 512 && tid < 512 + TPG) {
        const int t  = tid - 512;
        const int bi = sbi5[t];
        const float* p  = pb + ((size_t)b * NA + bi) * 4;
        const float* tg = tb + ((size_t)b * NT + g * TPG + t) * 4;
        float b1x1 = p[0],  b1y1 = p[1],  b1x2 = p[2],  b1y2 = p[3];
        float b2x1 = tg[0], b2y1 = tg[1], b2x2 = tg[2], b2y2 = tg[3];

        float area1 = (b1x2 - b1x1) * (b1y2 - b1y1);
        float area2 = (b2x2 - b2x1) * (b2y2 - b2y1);
        float iw = fmaxf(fminf(b1x2, b2x2) - fmaxf(b1x1, b2x1), 0.0f);
        float ih = fmaxf(fminf(b1y2, b2y2) - fmaxf(b1y1, b2y1), 0.0f);
        float inter = iw * ih;
        float iou = inter / (area1 + area2 - inter + F_EPS);

        float cdx = fmaxf(b1x2, b2x2) - fminf(b1x1, b2x1);
        float cdy = fmaxf(b1y2, b2y2) - fminf(b1y1, b2y1);
        float c_diag = cdx * cdx + cdy * cdy;

        float cx = (b1x1 + b1x2 - b2x1 - b2x2) * 0.5f;
        float cy = (b1y1 + b1y2 - b2y1 - b2y2) * 0.5f;
        float center_dist = cx * cx + cy * cy;

        float w1 = b1x2 - b1x1, h1 = b1y2 - b1y1;
        float w2 = b2x2 - b2x1, h2 = b2y2 - b2y1;
        float dat = atanf(w2 / h2) - atanf(w1 / h1);
        float vv = (float)(4.0 / (M_PI * M_PI)) * dat * dat;
        float alpha = vv / (1.0f - iou + vv + F_EPS);
        float ciou = iou - center_dist / c_diag - alpha * vv;
        s += W_BOX * (1.0f - ciou);
    }

    // bulk objectness: this block's 480-float4 slice of pc (no mask needed)
    if (tid < OBJ_F4_PER_BLK) {
        float4 v4 = pc4[blockIdx.x * OBJ_F4_PER_BLK + tid];
        s += W_OBJ * (bce0(v4.x) + bce0(v4.y) + bce0(v4.z) + bce0(v4.w));
    }

    // block reduce -> part[blockIdx.x]
    #pragma unroll
    for (int m = 32; m > 0; m >>= 1) s += __shfl_down(s, m);
    if (lane == 0) swred[wave] = s;
    __syncthreads();
    if (tid < KA_WAVES) {
        float v = swred[tid];
        #pragma unroll
        for (int m = 8; m > 0; m >>= 1) v += __shfl_down(v, m);
        if (tid == 0) part[blockIdx.x] = v;
    }
}

// ---- Node B: sum partials + dedup'd objectness correction (1 block) ----
__global__ __launch_bounds__(256) void kB(
        const float* __restrict__ pc,
        const int* __restrict__ best_idx,
        const float* __restrict__ part,
        float* __restrict__ out) {
    const int tid = threadIdx.x;
    const int wave = tid >> 6;
    const int lane = tid & 63;

    __shared__ int   sbi[NB * NT];
    __shared__ float swred[4];

    for (int i = tid; i < NB * NT; i += 256) sbi[i] = best_idx[i];
    __syncthreads();

    float s = 0.0f;
    if (tid < KA_BLOCKS) s += part[tid];

    // obj correction: bce(x,1)-bce(x,0) = -x, once per UNIQUE best anchor per image
    for (int i = tid; i < NB * NT; i += 256) {
        const int b = i / NT;
        const int t = i - b * NT;
        const int bi = sbi[i];
        bool dup = false;
        for (int tp = 0; tp < t; ++tp)
            if (sbi[b * NT + tp] == bi) dup = true;
        if (!dup) s -= W_OBJ * pc[(size_t)b * NA + bi];
    }

    #pragma unroll
    for (int m = 32; m > 0; m >>= 1) s += __shfl_down(s, m);
    if (lane == 0) swred[wave] = s;
    __syncthreads();
    if (tid == 0) out[0] = swred[0] + swred[1] + swred[2] + swred[3];
}

extern "C" void kernel_launch(void* const* d_in, const int* in_sizes, int n_in,
                              void* d_out, int out_size, void* d_ws, size_t ws_size,
                              hipStream_t stream) {
    const float* pb   = (const float*)d_in[0];   // (B,A,4)
    const float* pc   = (const float*)d_in[1];   // (B,A,1)
    const float* pcls = (const float*)d_in[2];   // (B,A,C)
    const float* tb   = (const float*)d_in[3];   // (B,T,4)
    const int*   tl   = (const int*)d_in[4];     // (B,T)

    char* ws = (char*)d_ws;
    float* part     = (float*)ws;             // 160 floats
    int*   best_idx = (int*)(ws + 1024);      // 800 ints

    kA<<<KA_BLOCKS, KA_THREADS, 0, stream>>>(pb, pc, pcls, tb, tl, best_idx, part);
    kB<<<1, 256, 0, stream>>>(pc, best_idx, part, (float*)d_out);
}

// Round 11
// 34.644 us; speedup vs baseline: 2.9231x; 1.2027x over previous
//
#include <hip/hip_runtime.h>
#include <math.h>

#define NB 16
#define NA 19200
#define NT 50
#define NC 80
#define LAMBDA_COORD 5.0f
#define F_EPS 1e-6f

// Node A: block = (image, group of TPG targets). Full-anchor scan per block.
#define TPG 5
#define NGRP (NT / TPG)          // 10
#define KA_BLOCKS (NB * NGRP)    // 160
#define KA_THREADS 1024
#define KA_WAVES (KA_THREADS / 64)
#define OBJ_F4_PER_BLK (NB * NA / 4 / KA_BLOCKS)   // 480 float4s of pc per block

#define W_OBJ (1.0f / (float)(NB * NA))
#define W_BOX (LAMBDA_COORD / (float)(NB * NT))
#define W_CLS (1.0f / (float)(NB * NT * NC))

// ws layout: [0..1024) float part[160]; [1024..4224) int best_idx[800]

__device__ __forceinline__ float bce0(float x) {   // bce_logits(x, 0)
    return fmaxf(x, 0.0f) + log1pf(expf(-fabsf(x)));
}

// ---- Node A: argmax (fast-rcp + depth-2 prefetch) + CIoU + cls BCE + obj slice ----
__global__ __launch_bounds__(1024) void kA(
        const float* __restrict__ pb,
        const float* __restrict__ pc,
        const float* __restrict__ pcls,
        const float* __restrict__ tb,
        const int* __restrict__ tl,
        int* __restrict__ best_idx,
        float* __restrict__ part) {
    const float4* pb4 = (const float4*)pb;
    const float4* tb4 = (const float4*)tb;
    const float4* pc4 = (const float4*)pc;

    const int b   = blockIdx.x / NGRP;
    const int g   = blockIdx.x % NGRP;
    const int tid = threadIdx.x;
    const int wave = tid >> 6;
    const int lane = tid & 63;

    float4 t4[TPG];
    float  ta[TPG];
    #pragma unroll
    for (int i = 0; i < TPG; ++i) {
        t4[i] = tb4[b * NT + g * TPG + i];
        ta[i] = (t4[i].z - t4[i].x) * (t4[i].w - t4[i].y) + F_EPS;  // fold EPS
    }

    float best[TPG];
    int   bidx[TPG];
    #pragma unroll
    for (int i = 0; i < TPG; ++i) { best[i] = -1.0f; bidx[i] = NA; }

    // ---- depth-2 software-pipelined scan (ascending a -> first-idx ties kept) ----
    const size_t boff = (size_t)b * NA;
    int a0 = tid;
    float4 p0 = pb4[boff + a0];
    int a1 = a0 + KA_THREADS;
    bool h1 = a1 < NA;
    float4 p1;
    if (h1) p1 = pb4[boff + a1];

    while (true) {
        const int a2 = a1 + KA_THREADS;
        const bool h2 = h1 && (a2 < NA);
        float4 p2;
        if (h2) p2 = pb4[boff + a2];

        // compute on p0 / a0
        {
            float area1 = (p0.z - p0.x) * (p0.w - p0.y);
            #pragma unroll
            for (int i = 0; i < TPG; ++i) {
                float ix1 = fmaxf(p0.x, t4[i].x), iy1 = fmaxf(p0.y, t4[i].y);
                float ix2 = fminf(p0.z, t4[i].z), iy2 = fminf(p0.w, t4[i].w);
                float inter = fmaxf(ix2 - ix1, 0.0f) * fmaxf(iy2 - iy1, 0.0f);
                float u = area1 + ta[i] - inter;          // union + EPS (EPS folded in ta)
                float iou = inter * __builtin_amdgcn_rcpf(u);
                if (iou > best[i]) { best[i] = iou; bidx[i] = a0; }
            }
        }

        if (!h1) break;
        p0 = p1; a0 = a1;
        p1 = p2; a1 = a2; h1 = h2;
    }

    __shared__ float swv[KA_WAVES][TPG];
    __shared__ int   swi[KA_WAVES][TPG];
    __shared__ int   sbi5[TPG];
    __shared__ float swred[KA_WAVES];

    #pragma unroll
    for (int i = 0; i < TPG; ++i) {
        float v = best[i];
        int   ix = bidx[i];
        #pragma unroll
        for (int m = 1; m < 64; m <<= 1) {
            float ov = __shfl_xor(v, m);
            int   oi = __shfl_xor(ix, m);
            if (ov > v || (ov == v && oi < ix)) { v = ov; ix = oi; }
        }
        if (lane == 0) { swv[wave][i] = v; swi[wave][i] = ix; }
    }
    __syncthreads();

    if (tid < TPG) {
        float v = swv[0][tid];
        int   ix = swi[0][tid];
        #pragma unroll
        for (int w = 1; w < KA_WAVES; ++w) {
            float ov = swv[w][tid];
            int   oi = swi[w][tid];
            if (ov > v || (ov == v && oi < ix)) { v = ov; ix = oi; }
        }
        best_idx[b * NT + g * TPG + tid] = ix;
        sbi5[tid] = ix;
    }
    __syncthreads();

    // ---------- epilogue: weighted per-thread accumulator ----------
    float s = 0.0f;

    // cls BCE for this block's 5 targets: threads 0..399, one (t,c) each
    if (tid < TPG * NC) {
        const int t = tid / NC;
        const int c = tid - t * NC;
        float x = pcls[((size_t)b * NA + sbi5[t]) * NC + c];
        int lab = tl[b * NT + g * TPG + t];
        s += W_CLS * (bce0(x) - (lab == c ? x : 0.0f));
    }

    // CIoU for this block's 5 targets (threads 512..516, exact reference formula)
    if (tid >= 512 && tid < 512 + TPG) {
        const int t  = tid - 512;
        const int bi = sbi5[t];
        const float* p  = pb + ((size_t)b * NA + bi) * 4;
        const float* tg = tb + ((size_t)b * NT + g * TPG + t) * 4;
        float b1x1 = p[0],  b1y1 = p[1],  b1x2 = p[2],  b1y2 = p[3];
        float b2x1 = tg[0], b2y1 = tg[1], b2x2 = tg[2], b2y2 = tg[3];

        float area1 = (b1x2 - b1x1) * (b1y2 - b1y1);
        float area2 = (b2x2 - b2x1) * (b2y2 - b2y1);
        float iw = fmaxf(fminf(b1x2, b2x2) - fmaxf(b1x1, b2x1), 0.0f);
        float ih = fmaxf(fminf(b1y2, b2y2) - fmaxf(b1y1, b2y1), 0.0f);
        float inter = iw * ih;
        float iou = inter / (area1 + area2 - inter + F_EPS);

        float cdx = fmaxf(b1x2, b2x2) - fminf(b1x1, b2x1);
        float cdy = fmaxf(b1y2, b2y2) - fminf(b1y1, b2y1);
        float c_diag = cdx * cdx + cdy * cdy;

        float cx = (b1x1 + b1x2 - b2x1 - b2x2) * 0.5f;
        float cy = (b1y1 + b1y2 - b2y1 - b2y2) * 0.5f;
        float center_dist = cx * cx + cy * cy;

        float w1 = b1x2 - b1x1, h1 = b1y2 - b1y1;
        float w2 = b2x2 - b2x1, h2 = b2y2 - b2y1;
        float dat = atanf(w2 / h2) - atanf(w1 / h1);
        float vv = (float)(4.0 / (M_PI * M_PI)) * dat * dat;
        float alpha = vv / (1.0f - iou + vv + F_EPS);
        float ciou = iou - center_dist / c_diag - alpha * vv;
        s += W_BOX * (1.0f - ciou);
    }

    // bulk objectness: this block's 480-float4 slice of pc (no mask needed)
    if (tid < OBJ_F4_PER_BLK) {
        float4 v4 = pc4[blockIdx.x * OBJ_F4_PER_BLK + tid];
        s += W_OBJ * (bce0(v4.x) + bce0(v4.y) + bce0(v4.z) + bce0(v4.w));
    }

    // block reduce -> part[blockIdx.x]
    #pragma unroll
    for (int m = 32; m > 0; m >>= 1) s += __shfl_down(s, m);
    if (lane == 0) swred[wave] = s;
    __syncthreads();
    if (tid < KA_WAVES) {
        float v = swred[tid];
        #pragma unroll
        for (int m = 8; m > 0; m >>= 1) v += __shfl_down(v, m);
        if (tid == 0) part[blockIdx.x] = v;
    }
}

// ---- Node B: sum partials + dedup'd objectness correction (1 block) ----
__global__ __launch_bounds__(256) void kB(
        const float* __restrict__ pc,
        const int* __restrict__ best_idx,
        const float* __restrict__ part,
        float* __restrict__ out) {
    const int tid = threadIdx.x;
    const int wave = tid >> 6;
    const int lane = tid & 63;

    __shared__ int   sbi[NB * NT];
    __shared__ float swred[4];

    for (int i = tid; i < NB * NT; i += 256) sbi[i] = best_idx[i];
    __syncthreads();

    float s = 0.0f;
    if (tid < KA_BLOCKS) s += part[tid];

    // obj correction: bce(x,1)-bce(x,0) = -x, once per UNIQUE best anchor per image
    for (int i = tid; i < NB * NT; i += 256) {
        const int b = i / NT;
        const int t = i - b * NT;
        const int bi = sbi[i];
        bool dup = false;
        for (int tp = 0; tp < t; ++tp)
            if (sbi[b * NT + tp] == bi) dup = true;
        if (!dup) s -= W_OBJ * pc[(size_t)b * NA + bi];
    }

    #pragma unroll
    for (int m = 32; m > 0; m >>= 1) s += __shfl_down(s, m);
    if (lane == 0) swred[wave] = s;
    __syncthreads();
    if (tid == 0) out[0] = swred[0] + swred[1] + swred[2] + swred[3];
}

extern "C" void kernel_launch(void* const* d_in, const int* in_sizes, int n_in,
                              void* d_out, int out_size, void* d_ws, size_t ws_size,
                              hipStream_t stream) {
    const float* pb   = (const float*)d_in[0];   // (B,A,4)
    const float* pc   = (const float*)d_in[1];   // (B,A,1)
    const float* pcls = (const float*)d_in[2];   // (B,A,C)
    const float* tb   = (const float*)d_in[3];   // (B,T,4)
    const int*   tl   = (const int*)d_in[4];     // (B,T)

    char* ws = (char*)d_ws;
    float* part     = (float*)ws;             // 160 floats
    int*   best_idx = (int*)(ws + 1024);      // 800 ints

    kA<<<KA_BLOCKS, KA_THREADS, 0, stream>>>(pb, pc, pcls, tb, tl, best_idx, part);
    kB<<<1, 256, 0, stream>>>(pc, best_idx, part, (float*)d_out);
}